// Round 9
// baseline (244.886 us; speedup 1.0000x reference)
//
#include <hip/hip_runtime.h>

#define N_NODES 50000
#define N_EDGES 800000

typedef __attribute__((ext_vector_type(8))) short short8;
typedef __attribute__((ext_vector_type(4))) float floatx4;

// float -> bf16 bits, round-to-nearest-even
static __device__ __forceinline__ unsigned short f2b(float f) {
    unsigned int u = __float_as_uint(f);
    unsigned int r = u + 0x7fffu + ((u >> 16) & 1u);
    return (unsigned short)(r >> 16);
}
static __device__ __forceinline__ unsigned int pk(float a, float b) {
    return (unsigned)f2b(a) | ((unsigned)f2b(b) << 16);
}
static __device__ __forceinline__ float blo(unsigned int u) {
    return __uint_as_float(u << 16);
}
static __device__ __forceinline__ float bhi(unsigned int u) {
    return __uint_as_float(u & 0xffff0000u);
}

// accumulate 4 bf16x8 rows into 8 fp32 lanes (same add tree as verified vers)
static __device__ __forceinline__ void acc4(float* f, uint4 v0, uint4 v1,
                                            uint4 v2, uint4 v3) {
    f[0] += (blo(v0.x) + blo(v1.x)) + (blo(v2.x) + blo(v3.x));
    f[1] += (bhi(v0.x) + bhi(v1.x)) + (bhi(v2.x) + bhi(v3.x));
    f[2] += (blo(v0.y) + blo(v1.y)) + (blo(v2.y) + blo(v3.y));
    f[3] += (bhi(v0.y) + bhi(v1.y)) + (bhi(v2.y) + bhi(v3.y));
    f[4] += (blo(v0.z) + blo(v1.z)) + (blo(v2.z) + blo(v3.z));
    f[5] += (bhi(v0.z) + bhi(v1.z)) + (bhi(v2.z) + bhi(v3.z));
    f[6] += (blo(v0.w) + blo(v1.w)) + (blo(v2.w) + blo(v3.w));
    f[7] += (bhi(v0.w) + bhi(v1.w)) + (bhi(v2.w) + bhi(v3.w));
}

// ---------------------------------------------------------------------------
// CSR build (R7 chain, unchanged): segments padded to x4, sentinel zero-row
// N_NODES; offsets via block-local scan + one atomicAdd per block.
// offpd = (off<<10 | padded_deg).
// ---------------------------------------------------------------------------
__global__ void hist_rank_kernel(const int* __restrict__ dst,
                                 int* __restrict__ deg, int* __restrict__ rank,
                                 int n) {
    int i = blockIdx.x * blockDim.x + threadIdx.x;
    if (i < n) rank[i] = atomicAdd(&deg[dst[i]], 1);
}

__global__ __launch_bounds__(1024) void offsets_kernel(
    const int* __restrict__ deg, int* __restrict__ offpd,
    int* __restrict__ gcount, unsigned short* __restrict__ nbr, int n) {
    __shared__ int s[1024];
    __shared__ int base;
    const int tid = threadIdx.x;
    const int i = blockIdx.x * 1024 + tid;
    const int d = (i < n) ? deg[i] : 0;
    const int pd = (d + 3) & ~3;
    s[tid] = pd;
    __syncthreads();
    for (int o = 1; o < 1024; o <<= 1) {
        int t = (tid >= o) ? s[tid - o] : 0;
        __syncthreads();
        s[tid] += t;
        __syncthreads();
    }
    if (tid == 1023) base = atomicAdd(gcount, s[1023]);
    __syncthreads();
    const int excl = base + s[tid] - pd;
    if (i < n) {
        offpd[i] = (excl << 10) | pd;
        for (int k = d; k < pd; ++k) nbr[excl + k] = (unsigned short)N_NODES;
    }
}

// Atomic-free edge scatter: pos = off(dst) + rank.
__global__ void fill_kernel(const int* __restrict__ src,
                            const int* __restrict__ dst,
                            const int* __restrict__ rank,
                            const int* __restrict__ offpd,
                            unsigned short* __restrict__ nbr, int n) {
    int i = blockIdx.x * blockDim.x + threadIdx.x;
    if (i < n) nbr[(offpd[dst[i]] >> 10) + rank[i]] = (unsigned short)src[i];
}

// ---------------------------------------------------------------------------
// Fused prep: weight transpose->bf16 [N][K] + x fp32->bf16 + deg/gcount
// zeroing + zero sentinel rows of xb and h (row N_NODES of each table).
// ---------------------------------------------------------------------------
__global__ __launch_bounds__(256) void prep_kernel(
    const float* __restrict__ W1a, const float* __restrict__ W1b,
    const float* __restrict__ W2a, const float* __restrict__ W2b,
    const float* __restrict__ x, unsigned short* __restrict__ W1aT,
    unsigned short* __restrict__ W1bT, unsigned short* __restrict__ W2aT,
    unsigned short* __restrict__ W2bT, unsigned short* __restrict__ xb,
    unsigned short* __restrict__ h, int* __restrict__ deg,
    int* __restrict__ gcount) {
    int i = blockIdx.x * 256 + threadIdx.x;
    if (i < 8192) {                       // W1a [64][128] -> [128][64]
        int n = i >> 6, k = i & 63;
        W1aT[i] = f2b(W1a[k * 128 + n]);
    } else if (i < 24576) {               // W1b [128][128] -> [128][128]
        int j = i - 8192, n = j >> 7, k = j & 127;
        W1bT[j] = f2b(W1b[k * 128 + n]);
    } else if (i < 40960) {               // W2a [128][128] -> [128][128]
        int j = i - 24576, n = j >> 7, k = j & 127;
        W2aT[j] = f2b(W2a[k * 128 + n]);
    } else if (i < 49152) {               // W2b [128][64] -> [64][128]
        int j = i - 40960, n = j >> 7, k = j & 127;
        W2bT[j] = f2b(W2b[k * 64 + n]);
    } else if (i < 49152 + N_NODES * 16) {  // x convert: float4 -> 4x bf16
        int j = i - 49152;
        float4 v = ((const float4*)x)[j];
        uint2 o;
        o.x = pk(v.x, v.y);
        o.y = pk(v.z, v.w);
        ((uint2*)xb)[j] = o;
    } else if (i < 49152 + N_NODES * 16 + N_NODES) {  // zero deg (+gcount)
        int j = i - (49152 + N_NODES * 16);
        deg[j] = 0;
        if (j == 0) *gcount = 0;
    } else {  // zero sentinel rows: xb row N (128B), h row N (256B)
        int j = i - (49152 + N_NODES * 16 + N_NODES);
        uint4 z = {0u, 0u, 0u, 0u};
        if (j < 8)
            ((uint4*)(xb + (size_t)N_NODES * 64))[j] = z;
        else if (j < 24)
            ((uint4*)(h + (size_t)N_NODES * 128))[j - 8] = z;
    }
}

// ---------------------------------------------------------------------------
// XCD-PINNED sliced gather. Block b runs on XCD (b&7) [dispatch round-robin
// heuristic — wrong mapping only costs speed]. That XCD handles ONE 64B
// column slice for the whole dispatch: slice = xcd % SLICES. Per-XCD touched
// bytes = 50K x 64B = 3.2MB < 4MB L2 -> neighbor row-slices go L2-resident
// (R8 failed because unpinned blocks cycled all slices per XCD). XCDs
// sharing a slice split the rows via part = xcd / SLICES.
// 4 lanes per 64B row-slice (uint4); indices as aligned uint2; 8 edges in
// flight. Per-column summation identical to R7/R8 -> bit-identical.
// Output: slice of t[node] (global, 64B coalesced per 4 lanes).
// ---------------------------------------------------------------------------
template <int DIN, int SLICES>
__global__ __launch_bounds__(256) void gather_sliced_kernel(
    const unsigned short* __restrict__ xin, const int* __restrict__ offpd,
    const unsigned short* __restrict__ nbr, unsigned short* __restrict__ tout,
    int n_rows, int rb_per_part) {
    constexpr int RS = DIN / 8;  // row stride in uint4
    const int b = blockIdx.x;
    const int xcd = b & 7;
    const int slice = xcd % SLICES;
    const int part = xcd / SLICES;
    const int rb = part * rb_per_part + (b >> 3);
    const int tid = threadIdx.x;
    const int grp = tid >> 2;  // 64 rows per block
    const int c = tid & 3;     // lane within 64B slice
    const int node = rb * 64 + grp;
    if (node >= n_rows) return;

    const int v = offpd[node];
    const int lo = v >> 10;
    const int hi = lo + (v & 1023);

    float f[8];
    const uint4* xr = (const uint4*)xin + slice * 4 + c;
    const uint4 a = xr[(size_t)node * RS];
    f[0] = blo(a.x); f[1] = bhi(a.x);
    f[2] = blo(a.y); f[3] = bhi(a.y);
    f[4] = blo(a.z); f[5] = bhi(a.z);
    f[6] = blo(a.w); f[7] = bhi(a.w);
    int j = lo;
    for (; j + 8 <= hi; j += 8) {
        const uint2 i0 = *(const uint2*)&nbr[j];
        const uint2 i1 = *(const uint2*)&nbr[j + 4];
        const int s0 = i0.x & 0xffff, s1 = i0.x >> 16;
        const int s2 = i0.y & 0xffff, s3 = i0.y >> 16;
        const int s4 = i1.x & 0xffff, s5 = i1.x >> 16;
        const int s6 = i1.y & 0xffff, s7 = i1.y >> 16;
        const uint4 v0 = xr[(size_t)s0 * RS];
        const uint4 v1 = xr[(size_t)s1 * RS];
        const uint4 v2 = xr[(size_t)s2 * RS];
        const uint4 v3 = xr[(size_t)s3 * RS];
        const uint4 v4 = xr[(size_t)s4 * RS];
        const uint4 v5 = xr[(size_t)s5 * RS];
        const uint4 v6 = xr[(size_t)s6 * RS];
        const uint4 v7 = xr[(size_t)s7 * RS];
        acc4(f, v0, v1, v2, v3);
        acc4(f, v4, v5, v6, v7);
    }
    if (j < hi) {  // exactly one 4-edge chunk remains (padding)
        const uint2 i0 = *(const uint2*)&nbr[j];
        const int s0 = i0.x & 0xffff, s1 = i0.x >> 16;
        const int s2 = i0.y & 0xffff, s3 = i0.y >> 16;
        const uint4 v0 = xr[(size_t)s0 * RS];
        const uint4 v1 = xr[(size_t)s1 * RS];
        const uint4 v2 = xr[(size_t)s2 * RS];
        const uint4 v3 = xr[(size_t)s3 * RS];
        acc4(f, v0, v1, v2, v3);
    }
    uint4 o;
    o.x = pk(f[0], f[1]);
    o.y = pk(f[2], f[3]);
    o.z = pk(f[4], f[5]);
    o.w = pk(f[6], f[7]);
    ((uint4*)tout)[(size_t)node * RS + slice * 4 + c] = o;
}

// ---------------------------------------------------------------------------
// 2-layer MLP via MFMA 16x16x32 bf16 (round-0 verified). Block = 256 thr,
// 64 rows; wave w owns rows [w*16, w*16+16) through both GEMMs (no barrier
// between phases). C/D layout: col=lane&15, row=quad*4+reg.
// ---------------------------------------------------------------------------
template <int DIN, int DH, int DOUT, bool OUT_BF16>
__global__ __launch_bounds__(256) void mlp_mfma_kernel(
    const unsigned short* __restrict__ t, const unsigned short* __restrict__ WaT,
    const float* __restrict__ ba, const unsigned short* __restrict__ WbT,
    const float* __restrict__ bb, void* __restrict__ outp, int n_rows) {
    constexpr int SA = DIN + 16;
    constexpr int SH = DH + 16;
    __shared__ __attribute__((aligned(16))) unsigned short tA[64 * SA];
    __shared__ __attribute__((aligned(16))) unsigned short hidA[64 * SH];

    const int tid = threadIdx.x;
    const int row0 = blockIdx.x * 64;

    constexpr int CHUNKS = 64 * DIN / 8;
    const uint4* tg = (const uint4*)t;
    for (int i = tid; i < CHUNKS; i += 256) {
        const int row = i / (DIN / 8);
        const int cb = i % (DIN / 8);
        uint4 v = {0u, 0u, 0u, 0u};
        const int gr = row0 + row;
        if (gr < n_rows) v = tg[(size_t)gr * (DIN / 8) + cb];
        *(uint4*)&tA[row * SA + cb * 8] = v;
    }
    __syncthreads();

    const int lane = tid & 63;
    const int wv = tid >> 6;
    const int quad = lane >> 4;
    const int l16 = lane & 15;
    const int m0 = wv * 16;

    short8 a1[DIN / 32];
#pragma unroll
    for (int kk = 0; kk < DIN / 32; ++kk)
        a1[kk] = *(const short8*)&tA[(m0 + l16) * SA + kk * 32 + quad * 8];
#pragma unroll
    for (int nt = 0; nt < DH / 16; ++nt) {
        floatx4 acc = {0.f, 0.f, 0.f, 0.f};
#pragma unroll
        for (int kk = 0; kk < DIN / 32; ++kk) {
            short8 b =
                *(const short8*)&WaT[(nt * 16 + l16) * DIN + kk * 32 + quad * 8];
            acc = __builtin_amdgcn_mfma_f32_16x16x32_bf16(a1[kk], b, acc, 0, 0, 0);
        }
        const float bias = ba[nt * 16 + l16];
#pragma unroll
        for (int r = 0; r < 4; ++r) {
            const float v = fmaxf(acc[r] + bias, 0.f);
            hidA[(m0 + quad * 4 + r) * SH + nt * 16 + l16] = f2b(v);
        }
    }
    // no barrier: each wave reads back only its own hidden strip

    short8 a2[DH / 32];
#pragma unroll
    for (int kk = 0; kk < DH / 32; ++kk)
        a2[kk] = *(const short8*)&hidA[(m0 + l16) * SH + kk * 32 + quad * 8];
#pragma unroll
    for (int nt = 0; nt < DOUT / 16; ++nt) {
        floatx4 acc = {0.f, 0.f, 0.f, 0.f};
#pragma unroll
        for (int kk = 0; kk < DH / 32; ++kk) {
            short8 b =
                *(const short8*)&WbT[(nt * 16 + l16) * DH + kk * 32 + quad * 8];
            acc = __builtin_amdgcn_mfma_f32_16x16x32_bf16(a2[kk], b, acc, 0, 0, 0);
        }
        const float bias = bb[nt * 16 + l16];
#pragma unroll
        for (int r = 0; r < 4; ++r) {
            const float v = fmaxf(acc[r] + bias, 0.f);
            const int grow = row0 + m0 + quad * 4 + r;
            if (grow < n_rows) {
                if (OUT_BF16)
                    ((unsigned short*)outp)[(size_t)grow * DOUT + nt * 16 + l16] =
                        f2b(v);
                else
                    ((float*)outp)[(size_t)grow * DOUT + nt * 16 + l16] = v;
            }
        }
    }
}

extern "C" void kernel_launch(void* const* d_in, const int* in_sizes, int n_in,
                              void* d_out, int out_size, void* d_ws,
                              size_t ws_size, hipStream_t stream) {
    const float* x   = (const float*)d_in[0];
    const int*   ei  = (const int*)d_in[1];  // [2, N_EDGES] int32
    const float* W1a = (const float*)d_in[2];
    const float* b1a = (const float*)d_in[3];
    const float* W1b = (const float*)d_in[4];
    const float* b1b = (const float*)d_in[5];
    const float* W2a = (const float*)d_in[6];
    const float* b2a = (const float*)d_in[7];
    const float* W2b = (const float*)d_in[8];
    const float* b2b = (const float*)d_in[9];
    float* out = (float*)d_out;

    const int* src = ei;
    const int* dst = ei + N_EDGES;

    // Workspace: bf16 xb[N+1,64] t1[N,64] h[N+1,128] t2[N,128] |
    //            bf16 weightsT | int deg/offpd/gcount/rank | ushort nbr[pad]
    unsigned short* xb = (unsigned short*)d_ws;
    unsigned short* t1 = xb + (size_t)(N_NODES + 1) * 64;
    unsigned short* h  = t1 + (size_t)N_NODES * 64;
    unsigned short* t2 = h + (size_t)(N_NODES + 1) * 128;
    unsigned short* W1aT = t2 + (size_t)N_NODES * 128;
    unsigned short* W1bT = W1aT + 8192;
    unsigned short* W2aT = W1bT + 16384;
    unsigned short* W2bT = W2aT + 16384;
    int* deg    = (int*)(W2bT + 8192);
    int* offpd  = deg + N_NODES;
    int* gcount = offpd + N_NODES;
    int* rank   = gcount + 64;  // 64-int pad keeps alignment
    unsigned short* nbr = (unsigned short*)(rank + N_EDGES);

    constexpr int NB = (N_NODES + 1023) / 1024;  // 49 scan blocks
    constexpr int PREP_THREADS = 49152 + N_NODES * 16 + N_NODES + 24;
    constexpr int NRB = (N_NODES + 63) / 64;  // 782 row-blocks

    // ---- Prep (weights + x convert + deg/gcount zero + sentinel rows) ----
    prep_kernel<<<(PREP_THREADS + 255) / 256, 256, 0, stream>>>(
        W1a, W1b, W2a, W2b, x, W1aT, W1bT, W2aT, W2bT, xb, h, deg, gcount);

    // ---- CSR build (padded to x4) ----
    hist_rank_kernel<<<(N_EDGES + 255) / 256, 256, 0, stream>>>(dst, deg, rank,
                                                                N_EDGES);
    offsets_kernel<<<NB, 1024, 0, stream>>>(deg, offpd, gcount, nbr, N_NODES);
    fill_kernel<<<(N_EDGES + 255) / 256, 256, 0, stream>>>(src, dst, rank,
                                                           offpd, nbr, N_EDGES);

    // ---- Layer 1: sliced gather (2 slices x 4 XCD-parts) + MLP ----
    {
        constexpr int PARTS = 8 / 2;                       // XCDs per slice
        constexpr int RBP = (NRB + PARTS - 1) / PARTS;     // 196
        gather_sliced_kernel<64, 2><<<8 * RBP, 256, 0, stream>>>(
            xb, offpd, nbr, t1, N_NODES, RBP);
    }
    mlp_mfma_kernel<64, 128, 128, true>
        <<<NRB, 256, 0, stream>>>(t1, W1aT, b1a, W1bT, b1b, h, N_NODES);

    // ---- Layer 2: sliced gather (4 slices x 2 XCD-parts) + MLP ----
    {
        constexpr int PARTS = 8 / 4;                       // XCDs per slice
        constexpr int RBP = (NRB + PARTS - 1) / PARTS;     // 391
        gather_sliced_kernel<128, 4><<<8 * RBP, 256, 0, stream>>>(
            h, offpd, nbr, t2, N_NODES, RBP);
    }
    mlp_mfma_kernel<128, 128, 64, false>
        <<<NRB, 256, 0, stream>>>(t2, W2aT, b2a, W2bT, b2b, out, N_NODES);
}